// Round 11
// baseline (257.837 us; speedup 1.0000x reference)
//
#include <hip/hip_runtime.h>
#include <math.h>

// DIAGNOSTIC ROUND: R8's proven kernel (23.3 us best) with the main scan
// loop amplified `reps`x (runtime arg, host passes 32). Each rep scans the
// SAME 32 col-tile pairs in a rep-rotated order ((j + rep*13) & 31), so the
// min-accumulation is idempotent -> bit-identical output, but the rotation
// makes addresses rep-dependent so the compiler cannot LICM/CSE the body.
// Purpose: k1 becomes ~50-500 us -> finally lands in rocprof top-5 with
// MfmaUtil / VALUBusy / Occupancy / bank-conflict counters, separating
// {MFMA-bound, VALU-issue-bound, latency-bound, conflict-bound, clock} and
// measuring the true marginal scan cost ((dur - stage)/32).
//
// Math (unchanged from R8):
//   A row i : {-2qx, -2qy, -2qz, 1, 1, 0...}   B col j : {cx, cy, cz, yh, yl, 0...}
//   MFMA -> yy_j - 2 q_i.c_j exactly; row-min + xx_i; all values exact ints.

typedef float  f32x4  __attribute__((ext_vector_type(4)));
typedef short  bf16x8 __attribute__((ext_vector_type(8)));

constexpr int NPTS  = 4096;
constexpr int BLK   = 256;
constexpr int QPB   = 64;             // query rows per block
constexpr int NTB   = NPTS / QPB;     // 64 row tiles per (dir, batch)
constexpr int BATCH = 4;
constexpr float FINF  = 3.402823466e38f;
constexpr float SCALE = 1.0f / 16384.0f;   // 1/(B*N) = 2^-14, exact

__device__ __forceinline__ float vox(float c, float off) {
    return truncf((c + off) / 0.05f);  // IEEE div: bit-matches reference
}
__device__ __forceinline__ unsigned bfbits(float v) {
    return __float_as_uint(v) >> 16;   // exact for the value classes used
}
__device__ __forceinline__ float min3(float a, float b, float c) {
    return fminf(fminf(a, b), c);      // clang fuses to v_min3_f32
}

__global__ __launch_bounds__(BLK) void chamfer_rows_kernel(
    const float* __restrict__ preds,
    const float* __restrict__ gts,
    float* __restrict__ partials,      // [512]
    int reps)                          // DIAGNOSTIC: work amplification
{
    __shared__ int4  cfrag[NPTS];      // candidate B-frags (64 KB)
    __shared__ int4  qfrag[QPB];       // query A-frags (prescaled -2, ones)
    __shared__ float qxx[QPB];         // query squared norms (exact ints)
    __shared__ float waveRow[4][QPB];

    const int t    = threadIdx.x;
    const int bid  = blockIdx.x;        // dir*256 + b*64 + tile
    const int dir  = bid >> 8;
    const int rem  = bid & 255;
    const int b    = rem >> 6;
    const int tile = rem & 63;
    const int w    = t >> 6;
    const int lane = t & 63;

    const float* __restrict__ xb = (dir ? gts : preds) + (size_t)b * NPTS * 3;
    const float* __restrict__ yb = (dir ? preds : gts) + (size_t)b * NPTS * 3;

    constexpr unsigned ONE = 0x3F80u;   // bf16 1.0

    // ---- stage candidates: voxelize, norms, split, pack B-frags ----
    for (int j = t; j < NPTS; j += BLK) {
        const float x = vox(yb[j*3+0], 3.0f);
        const float y = vox(yb[j*3+1], 3.0f);
        const float z = vox(yb[j*3+2], 1.0f);
        const float yy = fmaf(z, z, fmaf(y, y, x * x));      // exact int
        const float hi = floorf(yy * 0.00390625f) * 256.0f;  // exact
        const float lo = yy - hi;                            // in [0,256)
        cfrag[j] = make_int4(
            (int)((bfbits(y) << 16) | bfbits(x)),            // k0:cx k1:cy
            (int)((bfbits(hi) << 16) | bfbits(z)),           // k2:cz k3:yh
            (int)(bfbits(lo)),                               // k4:yl k5:0
            0);
    }
    // ---- stage this block's 64 query rows as A-frags ----
    if (t < QPB) {
        const int qi = tile * QPB + t;
        const float x = vox(xb[qi*3+0], 3.0f);
        const float y = vox(xb[qi*3+1], 3.0f);
        const float z = vox(xb[qi*3+2], 1.0f);
        qxx[t] = fmaf(z, z, fmaf(y, y, x * x));
        const float mx = -2.0f * x, my = -2.0f * y, mz = -2.0f * z; // exact
        qfrag[t] = make_int4(
            (int)((bfbits(my) << 16) | bfbits(mx)),          // k0 k1
            (int)((ONE << 16) | bfbits(mz)),                 // k2 k3:1
            (int)(ONE),                                      // k4:1 k5:0
            0);
    }
    __syncthreads();

    const int lq  = lane & 15;          // row (A) / col (B) within 16-tile
    const int grp = lane >> 4;          // lane group 0..3
    const bool lo_g = (grp == 0);       // k=0..7 carrier group

    // A fragments for the four 16-row query tiles (k-slots 8..31 = +0.0).
    bf16x8 afrag[4];
    #pragma unroll
    for (int rt = 0; rt < 4; ++rt) {
        const int4 qv = qfrag[rt * 16 + lq];
        int4 ai = { lo_g ? qv.x : 0, lo_g ? qv.y : 0, lo_g ? qv.z : 0, 0 };
        afrag[rt] = __builtin_bit_cast(bf16x8, ai);
    }

    f32x4 rm[4];
    #pragma unroll
    for (int rt = 0; rt < 4; ++rt) rm[rt] = (f32x4){FINF, FINF, FINF, FINF};
    const f32x4 zero = (f32x4){0.f, 0.f, 0.f, 0.f};

    // ---- main loop, repeated `reps` times in rotated order (idempotent) ----
    #pragma unroll 1
    for (int rep = 0; rep < reps; ++rep) {
        const int rot = (rep * 13) & 31;
        #pragma unroll 2
        for (int j = 0; j < 32; ++j) {
            const int jp = w * 32 + ((j + rot) & 31);
            const int jA = jp * 2, jB = jA + 1;
            const int4 bva = cfrag[jA * 16 + lq];   // b128, 4-way broadcast
            const int4 bvb = cfrag[jB * 16 + lq];
            const bf16x8 bfa = __builtin_bit_cast(bf16x8, bva);
            const bf16x8 bfb = __builtin_bit_cast(bf16x8, bvb);

            f32x4 dA[4], dB[4];
            #pragma unroll
            for (int rt = 0; rt < 4; ++rt)
                dA[rt] = __builtin_amdgcn_mfma_f32_16x16x32_bf16(
                    afrag[rt], bfa, zero, 0, 0, 0);
            #pragma unroll
            for (int rt = 0; rt < 4; ++rt)
                dB[rt] = __builtin_amdgcn_mfma_f32_16x16x32_bf16(
                    afrag[rt], bfb, zero, 0, 0, 0);

            #pragma unroll
            for (int rt = 0; rt < 4; ++rt) {
                #pragma unroll
                for (int i = 0; i < 4; ++i)
                    rm[rt][i] = min3(rm[rt][i], dA[rt][i], dB[rt][i]);
            }
        }
    }

    // ---- row-min wrap-up: min over the 16 cols held across lq lanes ----
    #pragma unroll
    for (int rt = 0; rt < 4; ++rt) {
        #pragma unroll
        for (int i = 0; i < 4; ++i) {
            float v = rm[rt][i];
            v = fminf(v, __shfl_xor(v, 1, 64));
            v = fminf(v, __shfl_xor(v, 2, 64));
            v = fminf(v, __shfl_xor(v, 4, 64));
            v = fminf(v, __shfl_xor(v, 8, 64));
            const int r = rt * 16 + grp * 4 + i;   // C/D row map (m89/m91)
            if (lq == 0) waveRow[w][r] = v + qxx[r];
        }
    }
    __syncthreads();

    if (w == 0) {                       // lane r owns query row r
        float v = fminf(fminf(waveRow[0][lane], waveRow[1][lane]),
                        fminf(waveRow[2][lane], waveRow[3][lane]));
        #pragma unroll
        for (int o = 32; o >= 1; o >>= 1) v += __shfl_xor(v, o, 64);
        if (lane == 0) partials[bid] = v;   // exact int sum of 64 row-mins
    }
}

// ---------------- k2: tiny fixed-order final reduce ----------------
__global__ __launch_bounds__(BLK) void chamfer_finish_kernel(
    const float* __restrict__ partials, float* __restrict__ out)
{
    __shared__ float s1[BLK];
    const int t = threadIdx.x;
    s1[t] = partials[t] + partials[t + 256];
    __syncthreads();
    for (int k = 128; k > 0; k >>= 1) {
        if (t < k) s1[t] += s1[t + k];
        __syncthreads();
    }
    if (t == 0) out[0] = s1[0] * SCALE;    // overwrite: no init needed
}

extern "C" void kernel_launch(void* const* d_in, const int* in_sizes, int n_in,
                              void* d_out, int out_size, void* d_ws, size_t ws_size,
                              hipStream_t stream)
{
    const float* preds = (const float*)d_in[0];
    const float* gts   = (const float*)d_in[1];
    float* out = (float*)d_out;
    float* partials = (float*)d_ws;        // 512 floats

    chamfer_rows_kernel<<<2 * BATCH * NTB, BLK, 0, stream>>>(
        preds, gts, partials, /*reps=*/32);
    chamfer_finish_kernel<<<1, BLK, 0, stream>>>(partials, out);
}

// Round 12
// 23.811 us; speedup vs baseline: 10.8285x; 10.8285x over previous
//
#include <hip/hip_runtime.h>
#include <math.h>

// Voxelized chamfer via bf16 MFMA (32x32x16 core), algebra in unused K-slots:
//   vox coords are integer-valued fp32, |v| <= ~160 -> EXACT in bf16.
//   A row i : {-2qx, -2qy, -2qz, 1, 1, 0...}   (-2q = exponent shift, exact)
//   B col j : { cx,   cy,   cz, yh, yl, 0...}  (yy = yh+yl exact bf16 split)
//   MFMA   -> yy_j - 2 q_i.c_j  directly; 16-term fp32 accum of exact ints
//   < 2^20 -> exact. row-min + xx_i = chamfer row-min; epilogue 1 min3/2evals.
//   loss = mean(row-mins, pred->gt) + mean(row-mins, gt->pred).
//
// R11 diagnostic: scan is VALU-issue-bound (VALUBusy 76% vs MfmaUtil 41%,
// 0 bank conflicts, 2 waves/SIMD). This round: 32x32x16 MFMA cuts MFMA
// instrs 4x and ds_reads 2x per eval (same min3 ratio) -> ~2x fewer issue
// slots per eval. K=16 layout: lanes 0-31 carry k0..7 (all 5 used slots);
// A-frag zero-masked on lanes>=32 makes B's k8..15 contribute 0 exactly.
// C/D map (m74/m101, HW-verified): col=lane&31, row=(reg&3)+8(reg>>2)+4(lane>>5).
//
// k1: 512 blocks = (dir, batch, 64-query tile) = 2 blocks/CU. Stage all 4096
//     candidates as packed 16B B-frags in LDS (float4-vectorized loads, all
//     IEEE divides here, bit-identical to reference). Each of 4 waves scans
//     32 col-tiles of 32 in pairs: 2 ds_read_b128 (imm offsets) + 4 MFMA +
//     32 min3. Row-min wrap-up: 5-level shfl min, +xx, cross-wave LDS min,
//     exact int sum -> partials[bid].
// k2: 1 block, fixed-order tree sum of 512 partials, out[0] = sum * 2^-14.

typedef float  f32x16 __attribute__((ext_vector_type(16)));
typedef short  bf16x8 __attribute__((ext_vector_type(8)));

constexpr int NPTS  = 4096;
constexpr int BLK   = 256;
constexpr int QPB   = 64;             // query rows per block (2 tiles of 32)
constexpr int NTB   = NPTS / QPB;     // 64 row tiles per (dir, batch)
constexpr int BATCH = 4;
constexpr float FINF  = 3.402823466e38f;
constexpr float SCALE = 1.0f / 16384.0f;   // 1/(B*N) = 2^-14, exact

__device__ __forceinline__ float vox(float c, float off) {
    return truncf((c + off) / 0.05f);  // IEEE div: bit-matches reference
}
__device__ __forceinline__ unsigned bfbits(float v) {
    return __float_as_uint(v) >> 16;   // exact for the value classes used
}
__device__ __forceinline__ float min3f(float a, float b, float c) {
    return fminf(fminf(a, b), c);      // clang fuses to v_min3_f32
}
__device__ __forceinline__ int4 packB(float x, float y, float z) {
    const float yy = fmaf(z, z, fmaf(y, y, x * x));      // exact int
    const float hi = floorf(yy * 0.00390625f) * 256.0f;  // exact
    const float lo = yy - hi;                            // in [0,256)
    return make_int4(
        (int)((bfbits(y) << 16) | bfbits(x)),            // k0:cx k1:cy
        (int)((bfbits(hi) << 16) | bfbits(z)),           // k2:cz k3:yh
        (int)(bfbits(lo)),                               // k4:yl k5:0
        0);
}

__global__ __launch_bounds__(BLK) void chamfer_rows_kernel(
    const float* __restrict__ preds,
    const float* __restrict__ gts,
    float* __restrict__ partials)      // [512]
{
    __shared__ int4  cfrag[NPTS];      // candidate B-frags (64 KB)
    __shared__ int4  qfrag[QPB];       // query A-frags (prescaled -2, ones)
    __shared__ float qxx[QPB];         // query squared norms (exact ints)
    __shared__ float waveRow[4][QPB];

    const int t    = threadIdx.x;
    const int bid  = blockIdx.x;        // dir*256 + b*64 + tile
    const int dir  = bid >> 8;
    const int rem  = bid & 255;
    const int b    = rem >> 6;
    const int tile = rem & 63;
    const int w    = t >> 6;
    const int lane = t & 63;

    const float* __restrict__ xb = (dir ? gts : preds) + (size_t)b * NPTS * 3;
    const float* __restrict__ yb = (dir ? preds : gts) + (size_t)b * NPTS * 3;

    constexpr unsigned ONE = 0x3F80u;   // bf16 1.0

    // ---- stage candidates: 4 consecutive points per thread per iter,
    //      3 float4 loads each (vectorized, coalesced 48B/lane) ----
    const float4* __restrict__ yb4 = (const float4*)yb;
    #pragma unroll
    for (int it = 0; it < 4; ++it) {
        const int p0 = it * 1024 + t * 4;
        const int fi = it * 768  + t * 3;
        const float4 r0 = yb4[fi + 0];
        const float4 r1 = yb4[fi + 1];
        const float4 r2 = yb4[fi + 2];
        cfrag[p0+0] = packB(vox(r0.x,3.f), vox(r0.y,3.f), vox(r0.z,1.f));
        cfrag[p0+1] = packB(vox(r0.w,3.f), vox(r1.x,3.f), vox(r1.y,1.f));
        cfrag[p0+2] = packB(vox(r1.z,3.f), vox(r1.w,3.f), vox(r2.x,1.f));
        cfrag[p0+3] = packB(vox(r2.y,3.f), vox(r2.z,3.f), vox(r2.w,1.f));
    }
    // ---- stage this block's 64 query rows as A-frags ----
    if (t < QPB) {
        const int qi = tile * QPB + t;
        const float x = vox(xb[qi*3+0], 3.0f);
        const float y = vox(xb[qi*3+1], 3.0f);
        const float z = vox(xb[qi*3+2], 1.0f);
        qxx[t] = fmaf(z, z, fmaf(y, y, x * x));
        const float mx = -2.0f * x, my = -2.0f * y, mz = -2.0f * z; // exact
        qfrag[t] = make_int4(
            (int)((bfbits(my) << 16) | bfbits(mx)),          // k0 k1
            (int)((ONE << 16) | bfbits(mz)),                 // k2 k3:1
            (int)(ONE),                                      // k4:1 k5:0
            0);
    }
    __syncthreads();

    const int col  = lane & 31;         // A row / B col within 32-tile
    const bool lo_g = (lane < 32);      // k=0..7 carrier half

    // A fragments for the two 32-row query tiles (lanes>=32: zero -> their
    // k8..15 products vanish exactly regardless of B bits there).
    bf16x8 afrag[2];
    #pragma unroll
    for (int rt = 0; rt < 2; ++rt) {
        const int4 qv = qfrag[rt * 32 + col];
        int4 ai = { lo_g ? qv.x : 0, lo_g ? qv.y : 0, lo_g ? qv.z : 0, 0 };
        afrag[rt] = __builtin_bit_cast(bf16x8, ai);
    }

    f32x16 rm[2];
    #pragma unroll
    for (int rt = 0; rt < 2; ++rt)
        #pragma unroll
        for (int i = 0; i < 16; ++i) rm[rt][i] = FINF;
    const f32x16 zero = {};

    // ---- main loop: 32 col-tiles per wave, in pairs; base+imm LDS addrs ----
    const int4* __restrict__ bbase = &cfrag[w * 1024 + col];
    #pragma unroll 4
    for (int jp = 0; jp < 16; ++jp) {
        const bf16x8 bfa = __builtin_bit_cast(bf16x8, bbase[jp * 64]);
        const bf16x8 bfb = __builtin_bit_cast(bf16x8, bbase[jp * 64 + 32]);

        const f32x16 dA0 = __builtin_amdgcn_mfma_f32_32x32x16_bf16(
            afrag[0], bfa, zero, 0, 0, 0);
        const f32x16 dB0 = __builtin_amdgcn_mfma_f32_32x32x16_bf16(
            afrag[0], bfb, zero, 0, 0, 0);
        const f32x16 dA1 = __builtin_amdgcn_mfma_f32_32x32x16_bf16(
            afrag[1], bfa, zero, 0, 0, 0);
        const f32x16 dB1 = __builtin_amdgcn_mfma_f32_32x32x16_bf16(
            afrag[1], bfb, zero, 0, 0, 0);

        #pragma unroll
        for (int i = 0; i < 16; ++i) {
            rm[0][i] = min3f(rm[0][i], dA0[i], dB0[i]);
            rm[1][i] = min3f(rm[1][i], dA1[i], dB1[i]);
        }
    }

    // ---- row-min wrap-up: min over 32 cols (5-level shfl within halves) ----
    const int hi4 = (lane >> 5) * 4;
    #pragma unroll
    for (int rt = 0; rt < 2; ++rt) {
        #pragma unroll
        for (int i = 0; i < 16; ++i) {
            float v = rm[rt][i];
            v = fminf(v, __shfl_xor(v, 1, 64));
            v = fminf(v, __shfl_xor(v, 2, 64));
            v = fminf(v, __shfl_xor(v, 4, 64));
            v = fminf(v, __shfl_xor(v, 8, 64));
            v = fminf(v, __shfl_xor(v, 16, 64));
            const int r = rt * 32 + (i & 3) + 8 * (i >> 2) + hi4; // m74/m101
            if (col == 0) waveRow[w][r] = v + qxx[r];
        }
    }
    __syncthreads();

    if (w == 0) {                       // lane r owns query row r
        float v = fminf(fminf(waveRow[0][lane], waveRow[1][lane]),
                        fminf(waveRow[2][lane], waveRow[3][lane]));
        #pragma unroll
        for (int o = 32; o >= 1; o >>= 1) v += __shfl_xor(v, o, 64);
        if (lane == 0) partials[bid] = v;   // exact int sum of 64 row-mins
    }
}

// ---------------- k2: tiny fixed-order final reduce ----------------
__global__ __launch_bounds__(BLK) void chamfer_finish_kernel(
    const float* __restrict__ partials, float* __restrict__ out)
{
    __shared__ float s1[BLK];
    const int t = threadIdx.x;
    s1[t] = partials[t] + partials[t + 256];
    __syncthreads();
    for (int k = 128; k > 0; k >>= 1) {
        if (t < k) s1[t] += s1[t + k];
        __syncthreads();
    }
    if (t == 0) out[0] = s1[0] * SCALE;    // overwrite: no init needed
}

extern "C" void kernel_launch(void* const* d_in, const int* in_sizes, int n_in,
                              void* d_out, int out_size, void* d_ws, size_t ws_size,
                              hipStream_t stream)
{
    const float* preds = (const float*)d_in[0];
    const float* gts   = (const float*)d_in[1];
    float* out = (float*)d_out;
    float* partials = (float*)d_ws;        // 512 floats

    chamfer_rows_kernel<<<2 * BATCH * NTB, BLK, 0, stream>>>(
        preds, gts, partials);
    chamfer_finish_kernel<<<1, BLK, 0, stream>>>(partials, out);
}